// Round 1
// baseline (758.920 us; speedup 1.0000x reference)
//
#include <hip/hip_runtime.h>
#include <hip/hip_bf16.h>

typedef __bf16 bf16_t;
typedef __bf16 bf16x4 __attribute__((ext_vector_type(4)));
typedef __bf16 bf16x8 __attribute__((ext_vector_type(8)));
typedef float f32x4 __attribute__((ext_vector_type(4)));

#define IGNORE_INDEX (-100)
#define N_ROWS 4096
#define H_DIM  1024
#define V_DIM  32000

#define BM 128
#define BN 128
#define BK 32
#define CT_NUM (V_DIM / BN)   /* 250 */

// ---------------- cast x: fp32 -> bf16, flat ----------------
__global__ __launch_bounds__(256) void k_cast_x(const float* __restrict__ in,
                                                bf16_t* __restrict__ out) {
  int i = (blockIdx.x * 256 + threadIdx.x) * 4;
  float4 v = *(const float4*)(in + i);
  bf16x4 o = { (bf16_t)v.x, (bf16_t)v.y, (bf16_t)v.z, (bf16_t)v.w };
  *(bf16x4*)(out + i) = o;
}

// ------------- transpose-cast weight: [H,V] fp32 -> [V,H] bf16 -------------
__global__ __launch_bounds__(256) void k_cast_wT(const float* __restrict__ w,
                                                 bf16_t* __restrict__ wT) {
  __shared__ float tile[32][33];
  int v0 = blockIdx.x * 32;
  int k0 = blockIdx.y * 32;
  int tx = threadIdx.x & 31;
  int ty = threadIdx.x >> 5;  // 0..7
#pragma unroll
  for (int r = 0; r < 32; r += 8)
    tile[ty + r][tx] = w[(size_t)(k0 + ty + r) * V_DIM + v0 + tx];
  __syncthreads();
#pragma unroll
  for (int r = 0; r < 32; r += 8)
    wT[(size_t)(v0 + ty + r) * H_DIM + k0 + tx] = (bf16_t)tile[tx][ty + r];
}

// ------------- fused GEMM tile + per-row max/sumexp partials -------------
// A: x_bf16 [N_ROWS][H_DIM], Bt: wT [V_DIM][H_DIM]
// partials laid out [row][ct] so the combine kernel reads coalesced.
__global__ __launch_bounds__(256) void k_gemm_lse(const bf16_t* __restrict__ A,
                                                  const bf16_t* __restrict__ Bt,
                                                  float* __restrict__ m_part,
                                                  float* __restrict__ s_part) {
  __shared__ __align__(16) bf16_t sA[BM * BK];
  __shared__ __align__(16) bf16_t sB[BN * BK];
  __shared__ float maxbuf[BM][2];
  __shared__ float sumbuf[BM][2];

  const int tid = threadIdx.x;
  const int ct = blockIdx.x;   // 0..249 column tile
  const int rt = blockIdx.y;   // 0..31  row tile
  const int m0 = rt * BM;
  const int n0 = ct * BN;

  const int w = tid >> 6;
  const int l = tid & 63;
  const int wr = w >> 1, wc = w & 1;
  const int quad = l >> 4, lc = l & 15;

  f32x4 acc[4][4];
#pragma unroll
  for (int i = 0; i < 4; ++i)
#pragma unroll
    for (int j = 0; j < 4; ++j)
      acc[i][j] = (f32x4){0.f, 0.f, 0.f, 0.f};

  const int e0 = tid * 8;           // element idx in 128x32 tile, issue 0
  const int e1 = (256 + tid) * 8;   // issue 1
  const int r0 = e0 >> 5, c0 = e0 & 31;
  const int r1 = e1 >> 5, c1 = e1 & 31;

  for (int kt = 0; kt < H_DIM / BK; ++kt) {
    const int k0 = kt * BK;
    __syncthreads();  // previous iter's ds_reads done before overwrite
    __builtin_amdgcn_global_load_lds(
        (const __attribute__((address_space(1))) void*)(A + (size_t)(m0 + r0) * H_DIM + k0 + c0),
        (__attribute__((address_space(3))) void*)(sA + e0), 16, 0, 0);
    __builtin_amdgcn_global_load_lds(
        (const __attribute__((address_space(1))) void*)(A + (size_t)(m0 + r1) * H_DIM + k0 + c1),
        (__attribute__((address_space(3))) void*)(sA + e1), 16, 0, 0);
    __builtin_amdgcn_global_load_lds(
        (const __attribute__((address_space(1))) void*)(Bt + (size_t)(n0 + r0) * H_DIM + k0 + c0),
        (__attribute__((address_space(3))) void*)(sB + e0), 16, 0, 0);
    __builtin_amdgcn_global_load_lds(
        (const __attribute__((address_space(1))) void*)(Bt + (size_t)(n0 + r1) * H_DIM + k0 + c1),
        (__attribute__((address_space(3))) void*)(sB + e1), 16, 0, 0);
    __syncthreads();  // drains vmcnt (global_load_lds) for all waves

    bf16x8 a_frag[4], b_frag[4];
#pragma unroll
    for (int i = 0; i < 4; ++i)
      a_frag[i] = *(const bf16x8*)(sA + (wr * 64 + i * 16 + lc) * BK + quad * 8);
#pragma unroll
    for (int j = 0; j < 4; ++j)
      b_frag[j] = *(const bf16x8*)(sB + (wc * 64 + j * 16 + lc) * BK + quad * 8);
#pragma unroll
    for (int i = 0; i < 4; ++i)
#pragma unroll
      for (int j = 0; j < 4; ++j)
        acc[i][j] = __builtin_amdgcn_mfma_f32_16x16x32_bf16(a_frag[i], b_frag[j], acc[i][j], 0, 0, 0);
  }

  // C/D layout: col = lane&15 (N-dim), row = quad*4 + reg (M-dim), per 16x16 frag.
  // Global row of acc[i][*][r] = m0 + wr*64 + i*16 + quad*4 + r
  // ---- per-row max over this block's 128 columns ----
  float rmax[4][4];
#pragma unroll
  for (int i = 0; i < 4; ++i)
#pragma unroll
    for (int r = 0; r < 4; ++r) {
      float mx = fmaxf(fmaxf(acc[i][0][r], acc[i][1][r]),
                       fmaxf(acc[i][2][r], acc[i][3][r]));
#pragma unroll
      for (int off = 1; off < 16; off <<= 1)
        mx = fmaxf(mx, __shfl_xor(mx, off, 64));
      rmax[i][r] = mx;
    }
  __syncthreads();
  if (lc == 0) {
#pragma unroll
    for (int i = 0; i < 4; ++i)
#pragma unroll
      for (int r = 0; r < 4; ++r)
        maxbuf[wr * 64 + i * 16 + quad * 4 + r][wc] = rmax[i][r];
  }
  __syncthreads();
  float rowmax[4][4];
#pragma unroll
  for (int i = 0; i < 4; ++i)
#pragma unroll
    for (int r = 0; r < 4; ++r) {
      int row = wr * 64 + i * 16 + quad * 4 + r;
      rowmax[i][r] = fmaxf(maxbuf[row][0], maxbuf[row][1]);
    }
  // ---- per-row sum of exp(logit - rowmax) ----
#pragma unroll
  for (int i = 0; i < 4; ++i)
#pragma unroll
    for (int r = 0; r < 4; ++r) {
      float s = __expf(acc[i][0][r] - rowmax[i][r]) + __expf(acc[i][1][r] - rowmax[i][r]) +
                __expf(acc[i][2][r] - rowmax[i][r]) + __expf(acc[i][3][r] - rowmax[i][r]);
#pragma unroll
      for (int off = 1; off < 16; off <<= 1)
        s += __shfl_xor(s, off, 64);
      if (lc == 0) sumbuf[wr * 64 + i * 16 + quad * 4 + r][wc] = s;
    }
  __syncthreads();
  if (wc == 0 && lc == 0) {
#pragma unroll
    for (int i = 0; i < 4; ++i)
#pragma unroll
      for (int r = 0; r < 4; ++r) {
        int row = wr * 64 + i * 16 + quad * 4 + r;
        size_t idx = (size_t)(m0 + row) * CT_NUM + ct;
        m_part[idx] = rowmax[i][r];
        s_part[idx] = sumbuf[row][0] + sumbuf[row][1];
      }
  }
}

// ------------- combine partials + target logit + masked sum -------------
__global__ __launch_bounds__(256) void k_combine(const float* __restrict__ x,
                                                 const bf16_t* __restrict__ wT,
                                                 const int* __restrict__ target,
                                                 const float* __restrict__ m_part,
                                                 const float* __restrict__ s_part,
                                                 float* __restrict__ out) {
  const int row = blockIdx.x * 4 + (threadIdx.x >> 6);  // one wave per row
  const int l = threadIdx.x & 63;
  // online logsumexp combine over 250 partials
  float m = -INFINITY, s = 0.f;
  for (int ctb = l; ctb < CT_NUM; ctb += 64) {
    float mj = m_part[(size_t)row * CT_NUM + ctb];
    float sj = s_part[(size_t)row * CT_NUM + ctb];
    float M = fmaxf(m, mj);
    s = s * __expf(m - M) + sj * __expf(mj - M);
    m = M;
  }
#pragma unroll
  for (int off = 1; off < 64; off <<= 1) {
    float mo = __shfl_xor(m, off, 64);
    float so = __shfl_xor(s, off, 64);
    float M = fmaxf(m, mo);
    s = s * __expf(m - M) + so * __expf(mo - M);
    m = M;
  }
  float lse = m + logf(s);
  int tgt = target[row];
  bool valid = (tgt != IGNORE_INDEX);
  int st = valid ? tgt : 0;
  // target logit: x[row] (fp32) . wT[st] (bf16, contiguous)
  const float* xr = x + (size_t)row * H_DIM;
  const bf16_t* wrow = wT + (size_t)st * H_DIM;
  float t = 0.f;
  for (int k = l; k < H_DIM; k += 64)
    t += xr[k] * (float)wrow[k];
#pragma unroll
  for (int off = 1; off < 64; off <<= 1)
    t += __shfl_xor(t, off, 64);
  if (l == 0 && valid) {
    atomicAdd(&out[0], lse - t);
    atomicAdd(&out[1], lse);
  }
}

extern "C" void kernel_launch(void* const* d_in, const int* in_sizes, int n_in,
                              void* d_out, int out_size, void* d_ws, size_t ws_size,
                              hipStream_t stream) {
  const float* x = (const float*)d_in[0];
  const float* w = (const float*)d_in[1];
  const int* target = (const int*)d_in[2];
  float* out = (float*)d_out;

  char* ws = (char*)d_ws;
  // ws layout (82,116,608 B total):
  //   x_bf16 : 4096*1024*2  =  8,388,608
  //   wT     : 32000*1024*2 = 65,536,000
  //   m_part : 4096*250*4   =  4,096,000
  //   s_part : 4096*250*4   =  4,096,000
  bf16_t* x_bf = (bf16_t*)ws;
  bf16_t* wT = (bf16_t*)(ws + 8388608);
  float* m_part = (float*)(ws + 8388608 + 65536000);
  float* s_part = (float*)(ws + 8388608 + 65536000 + 4096000);

  hipMemsetAsync(d_out, 0, (size_t)out_size * sizeof(float), stream);
  k_cast_x<<<dim3(N_ROWS * H_DIM / (256 * 4)), 256, 0, stream>>>(x, x_bf);
  k_cast_wT<<<dim3(V_DIM / 32, H_DIM / 32), 256, 0, stream>>>(w, wT);
  k_gemm_lse<<<dim3(CT_NUM, N_ROWS / BM), 256, 0, stream>>>(x_bf, wT, m_part, s_part);
  k_combine<<<dim3(N_ROWS / 4), 256, 0, stream>>>(x, wT, target, m_part, s_part, out);
}